// Round 19
// baseline (43.092 us; speedup 1.0000x reference)
//
#include <hip/hip_runtime.h>
#include <stdint.h>

#define Bn 8
#define Nn 2000
#define Cc 81
#define META_STRIDE (12 + Cc)
#define MAXI 100
#define MINCONF 0.7f
#define NMSTHR 0.3f
#define PB_ROIS 128  // ROIs per k_prep block (16000 / 128 = 125 blocks)
#define PSTRIDE 83   // LDS row stride (81 + 2 pad)
#define SELT 320     // radix-select target (>= 320 top keys selected)
#define SELCAP 512   // selection capacity == sort size

// map float to monotonically ordered uint (descending float == descending uint)
__device__ __forceinline__ uint32_t ford(float f) {
    uint32_t u = __float_as_uint(f);
    return (u & 0x80000000u) ? ~u : (u | 0x80000000u);
}

__device__ __forceinline__ unsigned long long shflx64(unsigned long long v, int lx) {
    unsigned int lo = (unsigned int)v, hi = (unsigned int)(v >> 32);
    lo = (unsigned int)__shfl_xor((int)lo, lx, 64);
    hi = (unsigned int)__shfl_xor((int)hi, lx, 64);
    return ((unsigned long long)hi << 32) | lo;
}

// ---------------- Kernel 1: LDS-staged argmax, delta apply, clip, sort key --
// (unchanged — verified absmax 0.0)
__global__ void __launch_bounds__(256)
k_prep(const float* __restrict__ rois,
       const float* __restrict__ probs,
       const float* __restrict__ bbox,
       const float* __restrict__ meta,
       float* __restrict__ refined,
       float* __restrict__ score,
       int* __restrict__ cls,
       unsigned long long* __restrict__ keys) {
    __shared__ float sp[PB_ROIS * PSTRIDE];   // 42.5 KB
    int tid  = threadIdx.x;
    int base = blockIdx.x * PB_ROIS;

    const float* gp = probs + (size_t)base * Cc;
    const int total = PB_ROIS * Cc;           // 10368
    int r = tid / Cc, c = tid - r * Cc;
    for (int idx = tid; idx < total; idx += 256) {
        sp[r * PSTRIDE + c] = gp[idx];
        r += 3; c += 13;                      // 256 = 3*81 + 13
        if (c >= Cc) { c -= Cc; r += 1; }
    }
    __syncthreads();

    int row  = tid >> 1;
    int half = tid & 1;
    const float* sr = sp + row * PSTRIDE;
    int   c0 = half ? 41 : 0;
    int   c1 = half ? Cc : 41;
    float v  = sr[c0];
    int   cb = c0;
    for (int cc2 = c0 + 1; cc2 < c1; ++cc2) {
        float x = sr[cc2];
        if (x > v) { v = x; cb = cc2; }       // first max wins within half
    }
    float vo = __shfl_xor(v, 1, 64);
    int   co = __shfl_xor(cb, 1, 64);
    float vA = half ? vo : v;   int cA = half ? co : cb;   // low half
    float vB = half ? v  : vo;  int cB = half ? cb : co;   // high half
    float sbest;  int cbest;
    if (vB > vA) { sbest = vB; cbest = cB; }  // tie -> low half (lower index)
    else         { sbest = vA; cbest = cA; }

    if (half) return;
    int t = base + row;

    float4 d4 = reinterpret_cast<const float4*>(bbox)[(size_t)t * Cc + cbest];
    float dy = d4.x * 0.1f, dx = d4.y * 0.1f, dh = d4.z * 0.2f, dw = d4.w * 0.2f;

    float4 r4 = reinterpret_cast<const float4*>(rois)[t];
    float y1 = r4.x, x1 = r4.y, y2 = r4.z, x2 = r4.w;
    float h = y2 - y1, w = x2 - x1;
    float cy = y1 + 0.5f * h + dy * h;
    float cx = x1 + 0.5f * w + dx * w;
    h = h * expf(dh);
    w = w * expf(dw);
    float ny1 = cy - 0.5f * h, nx1 = cx - 0.5f * w;
    float ny2 = cy + 0.5f * h, nx2 = cx + 0.5f * w;

    int b = t / Nn;
    float sy = meta[4] - 1.0f, sx = meta[5] - 1.0f;
    const float* mb = meta + (size_t)b * META_STRIDE;
    float wy1 = mb[7] / sy;
    float wx1 = mb[8] / sx;
    float wy2 = (mb[9]  - 1.0f) / sy;
    float wx2 = (mb[10] - 1.0f) / sx;

    ny1 = fminf(fmaxf(ny1, wy1), wy2);
    nx1 = fminf(fmaxf(nx1, wx1), wx2);
    ny2 = fminf(fmaxf(ny2, wy1), wy2);
    nx2 = fminf(fmaxf(nx2, wx1), wx2);

    reinterpret_cast<float4*>(refined)[t] = float4{ny1, nx1, ny2, nx2};
    score[t] = sbest;
    cls[t]   = cbest;

    int i = t - b * Nn;
    bool valid = (cbest > 0) && (sbest >= MINCONF);
    float ks = valid ? sbest : -1.0f;
    keys[t] = ((unsigned long long)ford(ks) << 32) |
              (unsigned long long)(0xFFFFFFFFu - (uint32_t)i);
}

// ---------------- Kernel 2: fused select + sort-512 + NMS + emit, 256 thr ---
// 256 threads (4 waves): every barrier syncs 4 waves, not 16. Single-level
// radix-select on key bits[55:48]: PROVABLE that all valid keys share top
// byte 0xBF (score in [0.7, 1.0] -> ford top byte 0xBF), so the level-1
// histogram of rounds 14-18 was degenerate and is deleted. Selection
// predicate valid && byte1 >= theta == old 16-bit-prefix test; no-crossing
// fallback theta=0 selects all valid. Sort/NMS/emit = verified code
// re-strided for 256 threads.
__global__ void __launch_bounds__(256, 1)
k_nms(const unsigned long long* __restrict__ keys,
      const float* __restrict__ refined,
      const float* __restrict__ score,
      const int* __restrict__ cls,
      float* __restrict__ out) {
    __shared__ unsigned long long sk[SELCAP];  // 4 KB
    __shared__ float4 sboxL[SELCAP];           // 8 KB
    __shared__ int h2[256], sc[257];
    __shared__ unsigned long long intraw[64];
    __shared__ unsigned long long extw[4];
    __shared__ int klist[128];
    __shared__ int sNk, sTheta, scnt;

    int b = blockIdx.x, tid = threadIdx.x;
    int wid = tid >> 6, lane = tid & 63;       // 4 waves
    int e0 = tid << 1;                         // covers 0..510

    // ---- load 8 keys/thread into registers (coalesced 512-stripes) ----
    const unsigned long long* kb = keys + (size_t)b * Nn;
    unsigned long long kr[8];
    #pragma unroll
    for (int p = 0; p < 4; ++p) {
        int e = (p << 9) + e0;
        kr[2 * p]     = (e     < Nn) ? kb[e]     : 0ull;
        kr[2 * p + 1] = (e + 1 < Nn) ? kb[e + 1] : 0ull;
    }
    h2[tid] = 0;
    sk[tid] = 0ull; sk[tid + 256] = 0ull;
    if (tid == 0) { sTheta = 0; scnt = 0; sNk = 0; sc[256] = 0; }
    __syncthreads();

    // ---- histogram bits[55:48] of valid keys ----
    #pragma unroll
    for (int p = 0; p < 8; ++p)
        if (kr[p] >> 63) atomicAdd(&h2[(int)(kr[p] >> 48) & 255], 1);
    __syncthreads();

    // ---- wave-0 suffix scan: sc[t] = # valid keys with byte1 >= t ----
    if (wid == 0) {
        int b0 = lane << 2;
        int v0 = h2[b0], v1 = h2[b0 + 1], v2 = h2[b0 + 2], v3 = h2[b0 + 3];
        int s3 = v3, s2 = v2 + s3, s1 = v1 + s2, s0 = v0 + s1;
        int G = s0;
        #pragma unroll
        for (int off = 1; off < 64; off <<= 1) {
            int u = __shfl_down(G, off, 64);
            if (lane + off < 64) G += u;
        }
        int A = G - s0;                        // sum over lanes > lane
        sc[b0] = A + s0; sc[b0 + 1] = A + s1; sc[b0 + 2] = A + s2; sc[b0 + 3] = A + s3;
    }
    __syncthreads();
    {
        int c = sc[tid], cn = sc[tid + 1];
        if (c >= SELT && cn < SELT) sTheta = tid;  // unique crossing; else 0
    }
    __syncthreads();

    // ---- compact selected keys into LDS ----
    unsigned th = (unsigned)sTheta;
    #pragma unroll
    for (int p = 0; p < 8; ++p) {
        unsigned long long k = kr[p];
        if ((k >> 63) && (((unsigned)(k >> 48) & 255u) >= th)) {
            int s = atomicAdd(&scnt, 1);
            if (s < SELCAP) sk[s] = k;
        }
    }
    __syncthreads();
    int S = scnt; if (S > SELCAP) S = SELCAP;

    // ---- sort-512 phase A: each wave sorts its 128-chunk in registers ----
    {
        unsigned long long a = sk[e0], bv = sk[e0 + 1];
        for (int k = 2; k <= 128; k <<= 1) {
            bool desc = ((e0 & k) == 0);
            for (int j = k >> 1; j >= 2; j >>= 1) {
                int lx = j >> 1;
                bool keepmax = (desc == ((lane & lx) == 0));
                unsigned long long oa = shflx64(a, lx);
                unsigned long long ob = shflx64(bv, lx);
                a  = keepmax ? (a  > oa ? a  : oa) : (a  < oa ? a  : oa);
                bv = keepmax ? (bv > ob ? bv : ob) : (bv < ob ? bv : ob);
            }
            bool sw = desc ? (a < bv) : (a > bv);
            if (sw) { unsigned long long t2 = a; a = bv; bv = t2; }
        }
        sk[e0] = a; sk[e0 + 1] = bv;
    }
    __syncthreads();

    // ---- sort-512 phase B: k = 256, 512 ----
    for (int k = 256; k <= SELCAP; k <<= 1) {
        for (int j = k >> 1; j >= 128; j >>= 1) {
            #pragma unroll
            for (int rep = 0; rep < 2; ++rep) {
                int t = tid + (rep << 8);
                int ixj = t ^ j;
                if (ixj > t) {
                    unsigned long long x = sk[t], y = sk[ixj];
                    bool desc = ((t & k) == 0);
                    if (desc ? (x < y) : (x > y)) { sk[t] = y; sk[ixj] = x; }
                }
            }
            __syncthreads();
        }
        {
            unsigned long long a = sk[e0], bv = sk[e0 + 1];
            bool desc = ((e0 & k) == 0);
            #pragma unroll
            for (int lx = 32; lx >= 1; lx >>= 1) {
                bool keepmax = (desc == ((lane & lx) == 0));
                unsigned long long oa = shflx64(a, lx);
                unsigned long long ob = shflx64(bv, lx);
                a  = keepmax ? (a  > oa ? a  : oa) : (a  < oa ? a  : oa);
                bv = keepmax ? (bv > ob ? bv : ob) : (bv < ob ? bv : ob);
            }
            bool sw = desc ? (a < bv) : (a > bv);
            if (sw) { unsigned long long t2 = a; a = bv; bv = t2; }
            sk[e0] = a; sk[e0 + 1] = bv;
        }
        __syncthreads();
    }

    // ---- stage offset-boxes (all selected are valid) ----
    for (int t = tid; t < S; t += 256) {
        uint32_t oi = 0xFFFFFFFFu - (uint32_t)(sk[t] & 0xFFFFFFFFull);
        int gi = b * Nn + (int)oi;
        float off = 4.0f * (float)cls[gi];    // CLASS_OFFSET * class_id
        float4 rf = reinterpret_cast<const float4*>(refined)[gi];
        sboxL[t] = float4{rf.x + off, rf.y + off, rf.z + off, rf.w + off};
    }
    __syncthreads();

    // ---- greedy NMS over 64-candidate blocks ----
    int nblocks = (S + 63) >> 6;
    for (int t = 0; t < nblocks; ++t) {
        int base = t << 6;
        int nb = S - base; if (nb > 64) nb = 64;
        int K = sNk;

        float4 cb = (lane < nb) ? sboxL[base + lane] : float4{0.f, 0.f, 0.f, 0.f};
        float a2 = (cb.z - cb.x) * (cb.w - cb.y);

        bool supext = false;
        for (int k = wid; k < K; k += 4) {
            float4 kbx = sboxL[klist[k]];
            float ar = (kbx.z - kbx.x) * (kbx.w - kbx.y);
            float iy = fmaxf(0.0f, fminf(kbx.z, cb.z) - fmaxf(kbx.x, cb.x));
            float ix = fmaxf(0.0f, fminf(kbx.w, cb.w) - fmaxf(kbx.y, cb.y));
            float inter = iy * ix;
            float iou = inter / (ar + a2 - inter + 1e-12f);
            supext |= (lane < nb) && (iou > NMSTHR);
        }
        unsigned long long bw = __ballot(supext);
        if (lane == 0) extw[wid] = bw;

        #pragma unroll
        for (int s = 0; s < 16; ++s) {
            int rr = (wid << 4) + s;          // 4 waves x 16 rows = 64
            bool sup = false;
            if (rr < nb && lane < nb && lane > rr) {
                float4 rb = sboxL[base + rr];
                float ar = (rb.z - rb.x) * (rb.w - rb.y);
                float iy = fmaxf(0.0f, fminf(rb.z, cb.z) - fmaxf(rb.x, cb.x));
                float ix = fmaxf(0.0f, fminf(rb.w, cb.w) - fmaxf(rb.y, cb.y));
                float inter = iy * ix;
                float iou = inter / (ar + a2 - inter + 1e-12f);
                sup = iou > NMSTHR;
            }
            unsigned long long rb2 = __ballot(sup);
            if (lane == 0) intraw[rr] = rb2;
        }
        __syncthreads();

        if (wid == 0) {
            unsigned long long intra_l = intraw[lane];
            unsigned long long e = (lane < 4) ? extw[lane] : 0ull;
            e |= shflx64(e, 2);
            e |= shflx64(e, 1);
            e = __shfl(e, 0, 64);              // broadcast full OR

            // scalar-mask greedy resolve (verified equivalent, round 18)
            unsigned long long candm =
                (nb < 64 ? ((1ull << nb) - 1ull) : ~0ull) & ~e;
            int nk = K;
            while (candm) {
                int i = __builtin_ctzll(candm);
                if (lane == 0) klist[nk] = base + i;
                ++nk;
                if (nk >= MAXI) break;
                unsigned long long rowi = __shfl(intra_l, i, 64);
                candm &= ~rowi & ~((2ull << i) - 1ull);
            }
            if (lane == 0) sNk = nk;
        }
        __syncthreads();
        if (sNk >= MAXI) break;
    }

    // ---- emit first min(100, kept) in sorted order; zero-fill tail ----
    int ne = sNk < MAXI ? sNk : MAXI;
    for (int r = tid; r < ne; r += 256) {
        int pos = klist[r];
        uint32_t oi = 0xFFFFFFFFu - (uint32_t)(sk[pos] & 0xFFFFFFFFull);
        int gi = b * Nn + (int)oi;
        float4 rf = reinterpret_cast<const float4*>(refined)[gi];
        float* orow = out + ((size_t)b * MAXI + r) * 6;
        orow[0] = rf.x;
        orow[1] = rf.y;
        orow[2] = rf.z;
        orow[3] = rf.w;
        orow[4] = (float)cls[gi];
        orow[5] = score[gi];
    }
    for (int tt = ne * 6 + tid; tt < MAXI * 6; tt += 256)
        out[(size_t)b * MAXI * 6 + tt] = 0.0f;
}

// ---------------- launch ----------------------------------------------------
extern "C" void kernel_launch(void* const* d_in, const int* in_sizes, int n_in,
                              void* d_out, int out_size, void* d_ws, size_t ws_size,
                              hipStream_t stream) {
    const float* rois  = (const float*)d_in[0];
    const float* probs = (const float*)d_in[1];
    const float* bbox  = (const float*)d_in[2];
    const float* meta  = (const float*)d_in[3];
    float* out = (float*)d_out;

    const int BN = Bn * Nn;
    char* ws = (char*)d_ws;
    size_t off = 0;
    auto alloc = [&](size_t bytes) {
        void* p = ws + off;
        off += (bytes + 255) & ~(size_t)255;
        return p;
    };
    float*              refined = (float*)              alloc((size_t)BN * 4 * sizeof(float));
    float*              score   = (float*)              alloc((size_t)BN * sizeof(float));
    int*                cls     = (int*)                alloc((size_t)BN * sizeof(int));
    unsigned long long* keys    = (unsigned long long*) alloc((size_t)BN * sizeof(unsigned long long));
    (void)ws_size; (void)in_sizes; (void)n_in; (void)out_size;

    k_prep<<<BN / PB_ROIS, 256, 0, stream>>>(rois, probs, bbox, meta,
                                             refined, score, cls, keys);
    k_nms<<<Bn, 256, 0, stream>>>(keys, refined, score, cls, out);
}

// Round 20
// 38.100 us; speedup vs baseline: 1.1310x; 1.1310x over previous
//
#include <hip/hip_runtime.h>
#include <stdint.h>

#define Bn 8
#define Nn 2000
#define Cc 81
#define META_STRIDE (12 + Cc)
#define MAXI 100
#define MINCONF 0.7f
#define NMSTHR 0.3f
#define PB_ROIS 128  // ROIs per k_prep block (16000 / 128 = 125 blocks)
#define PSTRIDE 83   // LDS row stride (81 + 2 pad)
#define SELT 320     // radix-select target (>= 320 top keys selected)
#define SELCAP 512   // selection capacity == sort size

// map float to monotonically ordered uint (descending float == descending uint)
__device__ __forceinline__ uint32_t ford(float f) {
    uint32_t u = __float_as_uint(f);
    return (u & 0x80000000u) ? ~u : (u | 0x80000000u);
}

__device__ __forceinline__ unsigned long long shflx64(unsigned long long v, int lx) {
    unsigned int lo = (unsigned int)v, hi = (unsigned int)(v >> 32);
    lo = (unsigned int)__shfl_xor((int)lo, lx, 64);
    hi = (unsigned int)__shfl_xor((int)hi, lx, 64);
    return ((unsigned long long)hi << 32) | lo;
}

// ---------------- Kernel 1: LDS-staged argmax, delta apply, clip, sort key --
// (unchanged — verified absmax 0.0)
__global__ void __launch_bounds__(256)
k_prep(const float* __restrict__ rois,
       const float* __restrict__ probs,
       const float* __restrict__ bbox,
       const float* __restrict__ meta,
       float* __restrict__ refined,
       float* __restrict__ score,
       int* __restrict__ cls,
       unsigned long long* __restrict__ keys) {
    __shared__ float sp[PB_ROIS * PSTRIDE];   // 42.5 KB
    int tid  = threadIdx.x;
    int base = blockIdx.x * PB_ROIS;

    const float* gp = probs + (size_t)base * Cc;
    const int total = PB_ROIS * Cc;           // 10368
    int r = tid / Cc, c = tid - r * Cc;
    for (int idx = tid; idx < total; idx += 256) {
        sp[r * PSTRIDE + c] = gp[idx];
        r += 3; c += 13;                      // 256 = 3*81 + 13
        if (c >= Cc) { c -= Cc; r += 1; }
    }
    __syncthreads();

    int row  = tid >> 1;
    int half = tid & 1;
    const float* sr = sp + row * PSTRIDE;
    int   c0 = half ? 41 : 0;
    int   c1 = half ? Cc : 41;
    float v  = sr[c0];
    int   cb = c0;
    for (int cc2 = c0 + 1; cc2 < c1; ++cc2) {
        float x = sr[cc2];
        if (x > v) { v = x; cb = cc2; }       // first max wins within half
    }
    float vo = __shfl_xor(v, 1, 64);
    int   co = __shfl_xor(cb, 1, 64);
    float vA = half ? vo : v;   int cA = half ? co : cb;   // low half
    float vB = half ? v  : vo;  int cB = half ? cb : co;   // high half
    float sbest;  int cbest;
    if (vB > vA) { sbest = vB; cbest = cB; }  // tie -> low half (lower index)
    else         { sbest = vA; cbest = cA; }

    if (half) return;
    int t = base + row;

    float4 d4 = reinterpret_cast<const float4*>(bbox)[(size_t)t * Cc + cbest];
    float dy = d4.x * 0.1f, dx = d4.y * 0.1f, dh = d4.z * 0.2f, dw = d4.w * 0.2f;

    float4 r4 = reinterpret_cast<const float4*>(rois)[t];
    float y1 = r4.x, x1 = r4.y, y2 = r4.z, x2 = r4.w;
    float h = y2 - y1, w = x2 - x1;
    float cy = y1 + 0.5f * h + dy * h;
    float cx = x1 + 0.5f * w + dx * w;
    h = h * expf(dh);
    w = w * expf(dw);
    float ny1 = cy - 0.5f * h, nx1 = cx - 0.5f * w;
    float ny2 = cy + 0.5f * h, nx2 = cx + 0.5f * w;

    int b = t / Nn;
    float sy = meta[4] - 1.0f, sx = meta[5] - 1.0f;
    const float* mb = meta + (size_t)b * META_STRIDE;
    float wy1 = mb[7] / sy;
    float wx1 = mb[8] / sx;
    float wy2 = (mb[9]  - 1.0f) / sy;
    float wx2 = (mb[10] - 1.0f) / sx;

    ny1 = fminf(fmaxf(ny1, wy1), wy2);
    nx1 = fminf(fmaxf(nx1, wx1), wx2);
    ny2 = fminf(fmaxf(ny2, wy1), wy2);
    nx2 = fminf(fmaxf(nx2, wx1), wx2);

    reinterpret_cast<float4*>(refined)[t] = float4{ny1, nx1, ny2, nx2};
    score[t] = sbest;
    cls[t]   = cbest;

    int i = t - b * Nn;
    bool valid = (cbest > 0) && (sbest >= MINCONF);
    float ks = valid ? sbest : -1.0f;
    keys[t] = ((unsigned long long)ford(ks) << 32) |
              (unsigned long long)(0xFFFFFFFFu - (uint32_t)i);
}

// ---------------- Kernel 2: fused radix-select + sort-512 + NMS + emit ------
// Round-15 configuration (best measured: 38.0 us, absmax 0.0). Two-level
// (8+8 bit) histogram select on key bits [63:48]; suffix sums via wave-0
// shfl scan. All ties at threshold included; if total valid < SELT all valid
// selected. Compaction straight into LDS (atomic slot, arbitrary order) —
// full re-sort of unique keys => deterministic. Sort-512 register-bitonic,
// blockwise NMS with ballot resolve, parallel emit.
__global__ void __launch_bounds__(1024, 1)
k_nms(const unsigned long long* __restrict__ keys,
      const float* __restrict__ refined,
      const float* __restrict__ score,
      const int* __restrict__ cls,
      float* __restrict__ out) {
    __shared__ unsigned long long sk[SELCAP];  // 4 KB
    __shared__ float4 sboxL[SELCAP];           // 8 KB
    __shared__ int h1[256], h2[256], sc[257];
    __shared__ unsigned long long intraw[64];
    __shared__ unsigned long long extw[16];
    __shared__ int klist[128];
    __shared__ int sNk, sB, sSuf, sTheta, scnt;

    int b = blockIdx.x, tid = threadIdx.x;
    int wid = tid >> 6, lane = tid & 63;
    int e0 = tid << 1;

    const unsigned long long* kb = keys + (size_t)b * Nn;
    unsigned long long k0 = (e0     < Nn) ? kb[e0]     : 0ull;
    unsigned long long k1 = (e0 + 1 < Nn) ? kb[e0 + 1] : 0ull;

    if (tid < 256) { h1[tid] = 0; h2[tid] = 0; }
    if (tid < SELCAP) sk[tid] = 0ull;
    if (tid == 0) { sB = -2; sSuf = 0; sTheta = 0x8000; scnt = 0; sNk = 0; sc[256] = 0; }
    __syncthreads();

    if (k0 >> 63) atomicAdd(&h1[(int)(k0 >> 56) & 255], 1);
    if (k1 >> 63) atomicAdd(&h1[(int)(k1 >> 56) & 255], 1);
    __syncthreads();

    // wave-0 suffix scan of h1 -> sc (sc[b] = # keys with top byte >= b)
    if (wid == 0) {
        int b0 = lane << 2;
        int v0 = h1[b0], v1 = h1[b0 + 1], v2 = h1[b0 + 2], v3 = h1[b0 + 3];
        int s3 = v3, s2 = v2 + s3, s1 = v1 + s2, s0 = v0 + s1;
        int G = s0;
        #pragma unroll
        for (int off = 1; off < 64; off <<= 1) {
            int u = __shfl_down(G, off, 64);
            if (lane + off < 64) G += u;
        }
        int A = G - s0;                        // sum over lanes > lane
        sc[b0] = A + s0; sc[b0 + 1] = A + s1; sc[b0 + 2] = A + s2; sc[b0 + 3] = A + s3;
    }
    __syncthreads();
    if (tid < 256) {
        int c = sc[tid], cn = sc[tid + 1];
        if (c >= SELT && cn < SELT) { sB = tid; sSuf = cn; }  // unique crossing
    }
    __syncthreads();
    int B = sB;                                // -2 => total valid < SELT

    if (B >= 0) {                              // uniform branch
        if ((k0 >> 63) && (((int)(k0 >> 56) & 255) == B))
            atomicAdd(&h2[(int)(k0 >> 48) & 255], 1);
        if ((k1 >> 63) && (((int)(k1 >> 56) & 255) == B))
            atomicAdd(&h2[(int)(k1 >> 48) & 255], 1);
        __syncthreads();
        if (wid == 0) {
            int b0 = lane << 2;
            int v0 = h2[b0], v1 = h2[b0 + 1], v2 = h2[b0 + 2], v3 = h2[b0 + 3];
            int s3 = v3, s2 = v2 + s3, s1 = v1 + s2, s0 = v0 + s1;
            int G = s0;
            #pragma unroll
            for (int off = 1; off < 64; off <<= 1) {
                int u = __shfl_down(G, off, 64);
                if (lane + off < 64) G += u;
            }
            int A = G - s0;
            sc[b0] = A + s0; sc[b0 + 1] = A + s1; sc[b0 + 2] = A + s2; sc[b0 + 3] = A + s3;
        }
        __syncthreads();
        if (tid < 256) {
            int c  = sSuf + sc[tid];
            int cn = sSuf + sc[tid + 1];
            if (c >= SELT && cn < SELT) sTheta = (B << 8) | tid;
        }
    }
    __syncthreads();

    // ---- compact selected keys into LDS ----
    unsigned th = (unsigned)sTheta;
    if ((unsigned)(k0 >> 48) >= th) {
        int s = atomicAdd(&scnt, 1);
        if (s < SELCAP) sk[s] = k0;
    }
    if ((unsigned)(k1 >> 48) >= th) {
        int s = atomicAdd(&scnt, 1);
        if (s < SELCAP) sk[s] = k1;
    }
    __syncthreads();
    int S = scnt; if (S > SELCAP) S = SELCAP;

    // ---- sort-512: phase A, waves 0-3 sort their 128-chunk in registers ----
    if (tid < 256) {
        unsigned long long a = sk[e0], bv = sk[e0 + 1];
        for (int k = 2; k <= 128; k <<= 1) {
            bool desc = ((e0 & k) == 0);
            for (int j = k >> 1; j >= 2; j >>= 1) {
                int lx = j >> 1;
                bool keepmax = (desc == ((lane & lx) == 0));
                unsigned long long oa = shflx64(a, lx);
                unsigned long long ob = shflx64(bv, lx);
                a  = keepmax ? (a  > oa ? a  : oa) : (a  < oa ? a  : oa);
                bv = keepmax ? (bv > ob ? bv : ob) : (bv < ob ? bv : ob);
            }
            bool sw = desc ? (a < bv) : (a > bv);
            if (sw) { unsigned long long t2 = a; a = bv; bv = t2; }
        }
        sk[e0] = a; sk[e0 + 1] = bv;
    }
    __syncthreads();

    // ---- sort-512: phase B, k = 256, 512 ----
    for (int k = 256; k <= SELCAP; k <<= 1) {
        for (int j = k >> 1; j >= 128; j >>= 1) {
            for (int t = tid; t < SELCAP; t += 1024) {
                int ixj = t ^ j;
                if (ixj > t) {
                    unsigned long long x = sk[t], y = sk[ixj];
                    bool desc = ((t & k) == 0);
                    if (desc ? (x < y) : (x > y)) { sk[t] = y; sk[ixj] = x; }
                }
            }
            __syncthreads();
        }
        if (tid < 256) {
            unsigned long long a = sk[e0], bv = sk[e0 + 1];
            bool desc = ((e0 & k) == 0);
            #pragma unroll
            for (int lx = 32; lx >= 1; lx >>= 1) {
                bool keepmax = (desc == ((lane & lx) == 0));
                unsigned long long oa = shflx64(a, lx);
                unsigned long long ob = shflx64(bv, lx);
                a  = keepmax ? (a  > oa ? a  : oa) : (a  < oa ? a  : oa);
                bv = keepmax ? (bv > ob ? bv : ob) : (bv < ob ? bv : ob);
            }
            bool sw = desc ? (a < bv) : (a > bv);
            if (sw) { unsigned long long t2 = a; a = bv; bv = t2; }
            sk[e0] = a; sk[e0 + 1] = bv;
        }
        __syncthreads();
    }

    // ---- stage offset-boxes (all selected are valid) ----
    for (int t = tid; t < S; t += 1024) {
        uint32_t oi = 0xFFFFFFFFu - (uint32_t)(sk[t] & 0xFFFFFFFFull);
        int gi = b * Nn + (int)oi;
        float off = 4.0f * (float)cls[gi];    // CLASS_OFFSET * class_id
        float4 rf = reinterpret_cast<const float4*>(refined)[gi];
        sboxL[t] = float4{rf.x + off, rf.y + off, rf.z + off, rf.w + off};
    }
    __syncthreads();

    // ---- greedy NMS over 64-candidate blocks ----
    int nblocks = (S + 63) >> 6;
    for (int t = 0; t < nblocks; ++t) {
        int base = t << 6;
        int nb = S - base; if (nb > 64) nb = 64;
        int K = sNk;

        float4 cb = (lane < nb) ? sboxL[base + lane] : float4{0.f, 0.f, 0.f, 0.f};
        float a2 = (cb.z - cb.x) * (cb.w - cb.y);

        bool supext = false;
        for (int k = wid; k < K; k += 16) {
            float4 kbx = sboxL[klist[k]];
            float ar = (kbx.z - kbx.x) * (kbx.w - kbx.y);
            float iy = fmaxf(0.0f, fminf(kbx.z, cb.z) - fmaxf(kbx.x, cb.x));
            float ix = fmaxf(0.0f, fminf(kbx.w, cb.w) - fmaxf(kbx.y, cb.y));
            float inter = iy * ix;
            float iou = inter / (ar + a2 - inter + 1e-12f);
            supext |= (lane < nb) && (iou > NMSTHR);
        }
        unsigned long long bw = __ballot(supext);
        if (lane == 0) extw[wid] = bw;

        #pragma unroll
        for (int s = 0; s < 4; ++s) {
            int rr = (wid << 2) + s;
            bool sup = false;
            if (rr < nb && lane < nb && lane > rr) {
                float4 rb = sboxL[base + rr];
                float ar = (rb.z - rb.x) * (rb.w - rb.y);
                float iy = fmaxf(0.0f, fminf(rb.z, cb.z) - fmaxf(rb.x, cb.x));
                float ix = fmaxf(0.0f, fminf(rb.w, cb.w) - fmaxf(rb.y, cb.y));
                float inter = iy * ix;
                float iou = inter / (ar + a2 - inter + 1e-12f);
                sup = iou > NMSTHR;
            }
            unsigned long long rb2 = __ballot(sup);
            if (lane == 0) intraw[rr] = rb2;
        }
        __syncthreads();

        if (wid == 0) {
            unsigned long long intra_l = intraw[lane];
            unsigned long long e = (lane < 16) ? extw[lane] : 0ull;
            #pragma unroll
            for (int m = 8; m >= 1; m >>= 1) e |= __shfl_xor(e, m, 64);
            e = __shfl(e, 0, 64);

            int nk = K;
            bool alive = (lane < nb) && !((e >> lane) & 1ull);
            unsigned long long candm = __ballot(alive);
            while (candm) {
                int i = __builtin_ctzll(candm);
                if (lane == 0) klist[nk] = base + i;
                ++nk;
                if (nk >= MAXI) break;
                unsigned long long rowi = __shfl(intra_l, i, 64);
                alive = alive && !((rowi >> lane) & 1ull);
                candm = __ballot(alive) & ~((2ull << i) - 1ull);
            }
            if (lane == 0) sNk = nk;
        }
        __syncthreads();
        if (sNk >= MAXI) break;
    }

    // ---- emit first min(100, kept) in sorted order; zero-fill tail ----
    int ne = sNk < MAXI ? sNk : MAXI;
    for (int r = tid; r < ne; r += 1024) {
        int pos = klist[r];
        uint32_t oi = 0xFFFFFFFFu - (uint32_t)(sk[pos] & 0xFFFFFFFFull);
        int gi = b * Nn + (int)oi;
        float4 rf = reinterpret_cast<const float4*>(refined)[gi];
        float* orow = out + ((size_t)b * MAXI + r) * 6;
        orow[0] = rf.x;
        orow[1] = rf.y;
        orow[2] = rf.z;
        orow[3] = rf.w;
        orow[4] = (float)cls[gi];
        orow[5] = score[gi];
    }
    for (int tt = ne * 6 + tid; tt < MAXI * 6; tt += 1024)
        out[(size_t)b * MAXI * 6 + tt] = 0.0f;
}

// ---------------- launch ----------------------------------------------------
extern "C" void kernel_launch(void* const* d_in, const int* in_sizes, int n_in,
                              void* d_out, int out_size, void* d_ws, size_t ws_size,
                              hipStream_t stream) {
    const float* rois  = (const float*)d_in[0];
    const float* probs = (const float*)d_in[1];
    const float* bbox  = (const float*)d_in[2];
    const float* meta  = (const float*)d_in[3];
    float* out = (float*)d_out;

    const int BN = Bn * Nn;
    char* ws = (char*)d_ws;
    size_t off = 0;
    auto alloc = [&](size_t bytes) {
        void* p = ws + off;
        off += (bytes + 255) & ~(size_t)255;
        return p;
    };
    float*              refined = (float*)              alloc((size_t)BN * 4 * sizeof(float));
    float*              score   = (float*)              alloc((size_t)BN * sizeof(float));
    int*                cls     = (int*)                alloc((size_t)BN * sizeof(int));
    unsigned long long* keys    = (unsigned long long*) alloc((size_t)BN * sizeof(unsigned long long));
    (void)ws_size; (void)in_sizes; (void)n_in; (void)out_size;

    k_prep<<<BN / PB_ROIS, 256, 0, stream>>>(rois, probs, bbox, meta,
                                             refined, score, cls, keys);
    k_nms<<<Bn, 1024, 0, stream>>>(keys, refined, score, cls, out);
}